// Round 5
// baseline (404.115 us; speedup 1.0000x reference)
//
#include <hip/hip_runtime.h>
#include <hip/hip_bf16.h>
#include <math.h>

#define N_NODES 50000
#define N_EDGES 800000
#define NFEAT 3
#define C1 512
#define C2 256
#define C3 128
#define NGRAPH 100
#define NCLS 2
#define PSPLIT 8

typedef short bh8 __attribute__((ext_vector_type(8)));   // 8 bf16 bit-patterns (4 VGPRs)
typedef float f32x4 __attribute__((ext_vector_type(4))); // MFMA accumulator

__device__ __forceinline__ short f2bf(float x) {
    __hip_bfloat16 h = __float2bfloat16(x);
    return *reinterpret_cast<short*>(&h);
}
__device__ __forceinline__ float bf2f(unsigned short s) {
    return __uint_as_float((unsigned int)s << 16);
}
__device__ __forceinline__ float bflo(unsigned int u) { return __uint_as_float(u << 16); }
__device__ __forceinline__ float bfhi(unsigned int u) { return __uint_as_float(u & 0xffff0000u); }

// ---------------- degree / normalization ----------------

__global__ void count_edges(const int* __restrict__ col, int* __restrict__ counts) {
    int e = blockIdx.x * blockDim.x + threadIdx.x;
    if (e < N_EDGES) atomicAdd(&counts[col[e]], 1);
}

__global__ void compute_dis(const int* __restrict__ counts, float* __restrict__ dis) {
    int i = blockIdx.x * blockDim.x + threadIdx.x;
    if (i < N_NODES) dis[i] = rsqrtf((float)(counts[i] + 1)); // +1 self loop; deg>=1 always
}

// ---------------- CSR build: 2-level scan + scatter ----------------

__global__ void scan_chunks(const int* __restrict__ counts, int* __restrict__ offsets,
                            int* __restrict__ chunksums) {
    __shared__ int s[256];
    int b = blockIdx.x, t = threadIdx.x;
    int i = b * 256 + t;
    int v = (i < N_NODES) ? counts[i] : 0;
    s[t] = v;
    __syncthreads();
    for (int d = 1; d < 256; d <<= 1) {
        int add = (t >= d) ? s[t - d] : 0;
        __syncthreads();
        s[t] += add;
        __syncthreads();
    }
    if (i < N_NODES) offsets[i + 1] = s[t];
    if (t == 255) chunksums[b] = s[255];
}

__global__ void scan_sums(int* __restrict__ chunksums, int nchunks) {
    __shared__ int s[256];
    int t = threadIdx.x;
    int v = (t < nchunks) ? chunksums[t] : 0;
    s[t] = v;
    __syncthreads();
    for (int d = 1; d < 256; d <<= 1) {
        int add = (t >= d) ? s[t - d] : 0;
        __syncthreads();
        s[t] += add;
        __syncthreads();
    }
    if (t < nchunks) chunksums[t] = (t == 0) ? 0 : s[t - 1];
}

__global__ void finalize_offsets(int* __restrict__ offsets, const int* __restrict__ chunkoffs) {
    int i = blockIdx.x * blockDim.x + threadIdx.x;
    if (i < N_NODES) offsets[i + 1] += chunkoffs[i / 256];
    if (i == 0) offsets[0] = 0;
}

__global__ void init_cursor(const int* __restrict__ offsets, int* __restrict__ cursor) {
    int i = blockIdx.x * blockDim.x + threadIdx.x;
    if (i < N_NODES) cursor[i] = offsets[i];
}

__global__ void scatter_edges(const int* __restrict__ rowi, const int* __restrict__ coli,
                              int* __restrict__ cursor, int* __restrict__ csr_src) {
    int e = blockIdx.x * blockDim.x + threadIdx.x;
    if (e < N_EDGES) {
        int r = rowi[e], c = coli[e];
        int p = atomicAdd(&cursor[c], 1);
        csr_src[p] = r;
    }
}

// ---------------- weight transpose + bf16 cast: W [K][Nn] f32 -> Wt [Nn][K] bf16 ----------------

__global__ void transp_bf16(const float* __restrict__ W, short* __restrict__ Wt, int K, int Nn) {
    int idx = blockIdx.x * 256 + threadIdx.x;
    if (idx < K * Nn) {
        int n = idx / K, k = idx % K;
        Wt[idx] = f2bf(W[k * Nn + n]);
    }
}

// ---------------- layer 1: aggregate 3 feats (dis-factored), then tiny GEMM ----------------
// aggx[i] = dis_i * ( dis_i*x[i] + sum_r dis_r*x[r] )

__global__ void agg_feat3(const float* __restrict__ x, const int* __restrict__ offsets,
                          const int* __restrict__ csr_src, const float* __restrict__ dis,
                          float* __restrict__ aggx) {
    int i = blockIdx.x * blockDim.x + threadIdx.x;
    if (i >= N_NODES) return;
    float di = dis[i];
    float a0 = di * x[i * 3 + 0], a1 = di * x[i * 3 + 1], a2 = di * x[i * 3 + 2];
    int s = offsets[i], e = offsets[i + 1];
    int p = s;
    for (; p + 4 <= e; p += 4) {
        int r0 = csr_src[p], r1 = csr_src[p + 1], r2 = csr_src[p + 2], r3 = csr_src[p + 3];
        float d0 = dis[r0], d1 = dis[r1], d2 = dis[r2], d3 = dis[r3];
        float3 v0 = *(const float3*)&x[r0 * 3];
        float3 v1 = *(const float3*)&x[r1 * 3];
        float3 v2 = *(const float3*)&x[r2 * 3];
        float3 v3 = *(const float3*)&x[r3 * 3];
        a0 += d0 * v0.x + d1 * v1.x + d2 * v2.x + d3 * v3.x;
        a1 += d0 * v0.y + d1 * v1.y + d2 * v2.y + d3 * v3.y;
        a2 += d0 * v0.z + d1 * v1.z + d2 * v2.z + d3 * v3.z;
    }
    for (; p < e; ++p) {
        int r = csr_src[p];
        float dr = dis[r];
        a0 += dr * x[r * 3 + 0];
        a1 += dr * x[r * 3 + 1];
        a2 += dr * x[r * 3 + 2];
    }
    aggx[i * 3 + 0] = di * a0; aggx[i * 3 + 1] = di * a1; aggx[i * 3 + 2] = di * a2;
}

// h1' = dis_i * relu(aggx@W1 + b1)   (pre-scaled for next layer's aggregation)
__global__ void layer1(const float* __restrict__ aggx, const float* __restrict__ W1,
                       const float* __restrict__ b1, const float* __restrict__ dis,
                       short* __restrict__ h1) {
    int i = blockIdx.x;
    int t = threadIdx.x; // 256 threads, 2 channels each
    float di = dis[i];
    float a0 = aggx[i * 3 + 0], a1 = aggx[i * 3 + 1], a2 = aggx[i * 3 + 2];
    int j0 = 2 * t, j1 = 2 * t + 1;
    float v0 = di * fmaxf(a0 * W1[j0] + a1 * W1[C1 + j0] + a2 * W1[2 * C1 + j0] + b1[j0], 0.f);
    float v1 = di * fmaxf(a0 * W1[j1] + a1 * W1[C1 + j1] + a2 * W1[2 * C1 + j1] + b1[j1], 0.f);
    unsigned int pk = (unsigned int)(unsigned short)f2bf(v0) |
                      ((unsigned int)(unsigned short)f2bf(v1) << 16);
    ((unsigned int*)h1)[(size_t)i * (C1 / 2) + t] = pk;
}

// ---------------- bf16 MFMA GEMM: C[M x Nn] = A[M x K] * Bt^T, Bt is [Nn][K] bf16 ----------------

template <int K>
__global__ __launch_bounds__(256, 2) void gemm_bf16(const short* __restrict__ A,
                                                    const short* __restrict__ Bt,
                                                    short* __restrict__ Cmat, int M, int Nn) {
    __shared__ short As[128 * 32];
    __shared__ short Bs[64 * 32];
    int bm = blockIdx.x * 128, bn = blockIdx.y * 64;
    int t = threadIdx.x;
    int wave = t >> 6, lane = t & 63, quad = lane >> 4, l16 = lane & 15;
    int wm = (wave >> 1) * 64, wn = (wave & 1) * 32;
    f32x4 acc[4][2] = {};

    int ar = t >> 1, ak = (t & 1) * 16;       // A: 128 rows x 32 cols, 32B per thread
    int br = t >> 2, bk = (t & 3) * 8;        // B: 64 rows x 32 cols, 16B per thread
    int agr = bm + ar; if (agr > M - 1) agr = M - 1; // clamp: rows >= M never stored
    const short* aptr = A + (size_t)agr * K + ak;
    const short* bptr = Bt + (size_t)(bn + br) * K + bk;

    for (int k0 = 0; k0 < K; k0 += 32) {
        *(bh8*)&As[ar * 32 + ak]     = *(const bh8*)(aptr + k0);
        *(bh8*)&As[ar * 32 + ak + 8] = *(const bh8*)(aptr + k0 + 8);
        *(bh8*)&Bs[br * 32 + bk]     = *(const bh8*)(bptr + k0);
        __syncthreads();
        bh8 af[4], bf[2];
#pragma unroll
        for (int mt = 0; mt < 4; ++mt)
            af[mt] = *(const bh8*)&As[(wm + mt * 16 + l16) * 32 + quad * 8];
#pragma unroll
        for (int nt = 0; nt < 2; ++nt)
            bf[nt] = *(const bh8*)&Bs[(wn + nt * 16 + l16) * 32 + quad * 8];
#pragma unroll
        for (int mt = 0; mt < 4; ++mt)
#pragma unroll
            for (int nt = 0; nt < 2; ++nt)
                acc[mt][nt] = __builtin_amdgcn_mfma_f32_16x16x32_bf16(af[mt], bf[nt], acc[mt][nt], 0, 0, 0);
        __syncthreads();
    }

#pragma unroll
    for (int mt = 0; mt < 4; ++mt)
#pragma unroll
        for (int nt = 0; nt < 2; ++nt) {
            int colc = bn + wn + nt * 16 + l16;
#pragma unroll
            for (int r = 0; r < 4; ++r) {
                int rowc = bm + wm + mt * 16 + quad * 4 + r;
                if (rowc < M) Cmat[(size_t)rowc * Nn + colc] = f2bf(acc[mt][nt][r]);
            }
        }
}

// ---- unweighted aggregation (messages pre-scaled by dis[src]); wave-per-node; pipelined ----
// out = [PRESCALE ? dis_i : 1] * relu( dis_i * (m[i] + sum_r m[r]) + bias )

template <int CPL>
__device__ __forceinline__ void addrow(const short* p, float (&acc)[CPL], bool init) {
    if constexpr (CPL == 4) {
        ushort4 u = *(const ushort4*)p;
        if (init) {
            acc[0] = bf2f(u.x); acc[1] = bf2f(u.y); acc[2] = bf2f(u.z); acc[3] = bf2f(u.w);
        } else {
            acc[0] += bf2f(u.x); acc[1] += bf2f(u.y); acc[2] += bf2f(u.z); acc[3] += bf2f(u.w);
        }
    } else {
        unsigned int u = *(const unsigned int*)p;
        if (init) { acc[0] = bflo(u); acc[1] = bfhi(u); }
        else      { acc[0] += bflo(u); acc[1] += bfhi(u); }
    }
}

template <int C, bool PRESCALE>
__global__ __launch_bounds__(256) void aggregate_ns(const short* __restrict__ m,
        const int* __restrict__ offsets, const int* __restrict__ csr_src,
        const float* __restrict__ dis, const float* __restrict__ bias,
        short* __restrict__ out) {
    constexpr int CPL = C / 64; // channels per lane (wave64 covers the row)
    int wave = threadIdx.x >> 6, lane = threadIdx.x & 63;
    int i = blockIdx.x * 4 + wave;
    if (i >= N_NODES) return;
    float di = dis[i];
    int co = lane * CPL;
    float acc[CPL];
    addrow<CPL>(m + (size_t)i * C + co, acc, true); // self term
    int s = offsets[i], e = offsets[i + 1];
    int p = s;
    int rr[8];
    bool have = (p + 8 <= e);
    if (have) {
#pragma unroll
        for (int q = 0; q < 8; ++q) rr[q] = __builtin_nontemporal_load(&csr_src[p + q]);
    }
    while (have) {
        int rn[8];
        bool nxt = (p + 16 <= e);
        if (nxt) {
#pragma unroll
            for (int q = 0; q < 8; ++q) rn[q] = __builtin_nontemporal_load(&csr_src[p + 8 + q]);
        }
#pragma unroll
        for (int q = 0; q < 8; ++q) addrow<CPL>(m + (size_t)rr[q] * C + co, acc, false);
        p += 8;
#pragma unroll
        for (int q = 0; q < 8; ++q) rr[q] = rn[q];
        have = nxt;
    }
    for (; p < e; ++p) {
        int r = __builtin_nontemporal_load(&csr_src[p]);
        addrow<CPL>(m + (size_t)r * C + co, acc, false);
    }
    float v[CPL];
#pragma unroll
    for (int k = 0; k < CPL; ++k) {
        v[k] = fmaxf(di * acc[k] + bias[co + k], 0.f);
        if (PRESCALE) v[k] *= di;
    }
    if constexpr (CPL == 4) {
        ushort4 o;
        o.x = (unsigned short)f2bf(v[0]); o.y = (unsigned short)f2bf(v[1]);
        o.z = (unsigned short)f2bf(v[2]); o.w = (unsigned short)f2bf(v[3]);
        *(ushort4*)&out[(size_t)i * C + co] = o;
    } else {
        unsigned int pk = (unsigned int)(unsigned short)f2bf(v[0]) |
                          ((unsigned int)(unsigned short)f2bf(v[1]) << 16);
        *(unsigned int*)&out[(size_t)i * C + co] = pk;
    }
}

// ---------------- two-stage mean pool: per-(graph,split) partial sums, few atomics ----------------

__global__ void pool_partial(const short* __restrict__ h3, const int* __restrict__ batch,
                             float* __restrict__ pooled) {
    int g = blockIdx.x, sp = blockIdx.y;
    int t = threadIdx.x; // 64 threads, 2 channels each (C3=128)
    __shared__ int seg[2];
    if (t < 2) {
        int target = g + t;
        int lo = 0, hi = N_NODES;
        while (lo < hi) { int mid = (lo + hi) >> 1; if (batch[mid] < target) lo = mid + 1; else hi = mid; }
        seg[t] = lo;
    }
    __syncthreads();
    int start = seg[0], end = seg[1];
    int len = end - start;
    int chunk = (len + PSPLIT - 1) / PSPLIT;
    int a = start + sp * chunk;
    int b = a + chunk; if (b > end) b = end;
    if (a >= b) return;
    const unsigned int* hu = (const unsigned int*)h3;
    float s0 = 0.f, s1 = 0.f;
    int i = a;
    for (; i + 4 <= b; i += 4) {
        unsigned int u0 = hu[(size_t)(i + 0) * (C3 / 2) + t];
        unsigned int u1 = hu[(size_t)(i + 1) * (C3 / 2) + t];
        unsigned int u2 = hu[(size_t)(i + 2) * (C3 / 2) + t];
        unsigned int u3 = hu[(size_t)(i + 3) * (C3 / 2) + t];
        s0 += bflo(u0) + bflo(u1) + bflo(u2) + bflo(u3);
        s1 += bfhi(u0) + bfhi(u1) + bfhi(u2) + bfhi(u3);
    }
    for (; i < b; ++i) {
        unsigned int u = hu[(size_t)i * (C3 / 2) + t];
        s0 += bflo(u);
        s1 += bfhi(u);
    }
    atomicAdd(&pooled[g * C3 + 2 * t], s0);
    atomicAdd(&pooled[g * C3 + 2 * t + 1], s1);
}

// ---------------- head: mean-divide + linear + log_softmax ----------------

__global__ void finalize_head(const float* __restrict__ pooled, const int* __restrict__ batch,
                              const float* __restrict__ Wc, const float* __restrict__ bc,
                              float* __restrict__ outp) {
    int g = blockIdx.x;
    int t = threadIdx.x; // 128 threads = C3
    __shared__ int seg[2];
    if (t < 2) {
        int target = g + t;
        int lo = 0, hi = N_NODES;
        while (lo < hi) { int mid = (lo + hi) >> 1; if (batch[mid] < target) lo = mid + 1; else hi = mid; }
        seg[t] = lo;
    }
    __syncthreads();
    float cnt = (float)(seg[1] - seg[0]);
    float pv = pooled[(size_t)g * C3 + t] / fmaxf(cnt, 1.f);
    float p0 = pv * Wc[t * 2 + 0];
    float p1 = pv * Wc[t * 2 + 1];
#pragma unroll
    for (int o = 32; o > 0; o >>= 1) {
        p0 += __shfl_down(p0, o);
        p1 += __shfl_down(p1, o);
    }
    __shared__ float r0[2], r1[2];
    int wid = t >> 6, lane = t & 63;
    if (lane == 0) { r0[wid] = p0; r1[wid] = p1; }
    __syncthreads();
    if (t == 0) {
        float l0 = r0[0] + r0[1] + bc[0];
        float l1 = r1[0] + r1[1] + bc[1];
        float mx = fmaxf(l0, l1);
        float lse = mx + logf(expf(l0 - mx) + expf(l1 - mx));
        outp[g * 2 + 0] = l0 - lse;
        outp[g * 2 + 1] = l1 - lse;
    }
}

// ---------------- launch ----------------

extern "C" void kernel_launch(void* const* d_in, const int* in_sizes, int n_in,
                              void* d_out, int out_size, void* d_ws, size_t ws_size,
                              hipStream_t stream) {
    const float* x = (const float*)d_in[0];
    const float* W1 = (const float*)d_in[1];
    const float* b1 = (const float*)d_in[2];
    const float* W2 = (const float*)d_in[3];
    const float* b2 = (const float*)d_in[4];
    const float* W3 = (const float*)d_in[5];
    const float* b3 = (const float*)d_in[6];
    const float* Wc = (const float*)d_in[7];
    const float* bc = (const float*)d_in[8];
    const int* ei = (const int*)d_in[9];
    const int* batch = (const int*)d_in[10];
    const int* row = ei;
    const int* col = ei + N_EDGES;
    float* out = (float*)d_out;

    char* ws = (char*)d_ws;
    size_t off = 0;
    auto alloc = [&](size_t bytes) -> void* {
        off = (off + 255) & ~(size_t)255;
        void* p = ws + off;
        off += bytes;
        return p;
    };

    int* counts = (int*)alloc((size_t)N_NODES * 4);
    int* offsets = (int*)alloc((size_t)(N_NODES + 1) * 4);
    int* cursor = (int*)alloc((size_t)N_NODES * 4);
    int* chunksums = (int*)alloc(256 * 4);
    float* dis = (float*)alloc((size_t)N_NODES * 4);
    int* csr_src = (int*)alloc((size_t)N_EDGES * 4);
    float* aggx = (float*)alloc((size_t)N_NODES * 3 * 4);
    short* W2t = (short*)alloc((size_t)C1 * C2 * 2);   // [C2][C1] bf16
    short* W3t = (short*)alloc((size_t)C2 * C3 * 2);   // [C3][C2] bf16
    short* h1 = (short*)alloc((size_t)N_NODES * C1 * 2);
    short* m2 = (short*)alloc((size_t)N_NODES * C2 * 2);
    short* h2 = (short*)alloc((size_t)N_NODES * C2 * 2);
    short* m3 = (short*)alloc((size_t)N_NODES * C3 * 2);
    short* h3 = (short*)alloc((size_t)N_NODES * C3 * 2);
    float* pooled = (float*)alloc((size_t)NGRAPH * C3 * 4);

    hipMemsetAsync(counts, 0, (size_t)N_NODES * 4, stream);
    hipMemsetAsync(pooled, 0, (size_t)NGRAPH * C3 * 4, stream);
    count_edges<<<(N_EDGES + 255) / 256, 256, 0, stream>>>(col, counts);
    compute_dis<<<(N_NODES + 255) / 256, 256, 0, stream>>>(counts, dis);
    int nchunks = (N_NODES + 255) / 256;
    scan_chunks<<<nchunks, 256, 0, stream>>>(counts, offsets, chunksums);
    scan_sums<<<1, 256, 0, stream>>>(chunksums, nchunks);
    finalize_offsets<<<(N_NODES + 255) / 256, 256, 0, stream>>>(offsets, chunksums);
    init_cursor<<<(N_NODES + 255) / 256, 256, 0, stream>>>(offsets, cursor);
    scatter_edges<<<(N_EDGES + 255) / 256, 256, 0, stream>>>(row, col, cursor, csr_src);

    transp_bf16<<<(C1 * C2 + 255) / 256, 256, 0, stream>>>(W2, W2t, C1, C2);
    transp_bf16<<<(C2 * C3 + 255) / 256, 256, 0, stream>>>(W3, W3t, C2, C3);

    agg_feat3<<<(N_NODES + 255) / 256, 256, 0, stream>>>(x, offsets, csr_src, dis, aggx);
    layer1<<<N_NODES, C1 / 2, 0, stream>>>(aggx, W1, b1, dis, h1);

    dim3 g2((N_NODES + 127) / 128, C2 / 64);
    gemm_bf16<C1><<<g2, 256, 0, stream>>>(h1, W2t, m2, N_NODES, C2);
    aggregate_ns<C2, true><<<(N_NODES + 3) / 4, 256, 0, stream>>>(m2, offsets, csr_src, dis, b2, h2);

    dim3 g3((N_NODES + 127) / 128, C3 / 64);
    gemm_bf16<C2><<<g3, 256, 0, stream>>>(h2, W3t, m3, N_NODES, C3);
    aggregate_ns<C3, false><<<(N_NODES + 3) / 4, 256, 0, stream>>>(m3, offsets, csr_src, dis, b3, h3);

    dim3 gp(NGRAPH, PSPLIT);
    pool_partial<<<gp, C3 / 2, 0, stream>>>(h3, batch, pooled);
    finalize_head<<<NGRAPH, C3, 0, stream>>>(pooled, batch, Wc, bc, out);
}

// Round 6
// 381.186 us; speedup vs baseline: 1.0602x; 1.0602x over previous
//
#include <hip/hip_runtime.h>
#include <hip/hip_bf16.h>
#include <math.h>

#define N_NODES 50000
#define N_EDGES 800000
#define NFEAT 3
#define C1 512
#define C2 256
#define C3 128
#define NGRAPH 100
#define NCLS 2
#define PSPLIT 8

typedef short bh8 __attribute__((ext_vector_type(8)));   // 8 bf16 bit-patterns (4 VGPRs)
typedef float f32x4 __attribute__((ext_vector_type(4))); // MFMA accumulator

__device__ __forceinline__ short f2bf(float x) {
    __hip_bfloat16 h = __float2bfloat16(x);
    return *reinterpret_cast<short*>(&h);
}
__device__ __forceinline__ float bflo(unsigned int u) { return __uint_as_float(u << 16); }
__device__ __forceinline__ float bfhi(unsigned int u) { return __uint_as_float(u & 0xffff0000u); }

// ---------------- degree / normalization ----------------

__global__ void count_edges(const int* __restrict__ col, int* __restrict__ counts) {
    int e = blockIdx.x * blockDim.x + threadIdx.x;
    if (e < N_EDGES) atomicAdd(&counts[col[e]], 1);
}

__global__ void compute_dis(const int* __restrict__ counts, float* __restrict__ dis) {
    int i = blockIdx.x * blockDim.x + threadIdx.x;
    if (i < N_NODES) dis[i] = rsqrtf((float)(counts[i] + 1)); // +1 self loop; deg>=1 always
}

// ---------------- CSR build: 2-level scan + scatter ----------------

__global__ void scan_chunks(const int* __restrict__ counts, int* __restrict__ offsets,
                            int* __restrict__ chunksums) {
    __shared__ int s[256];
    int b = blockIdx.x, t = threadIdx.x;
    int i = b * 256 + t;
    int v = (i < N_NODES) ? counts[i] : 0;
    s[t] = v;
    __syncthreads();
    for (int d = 1; d < 256; d <<= 1) {
        int add = (t >= d) ? s[t - d] : 0;
        __syncthreads();
        s[t] += add;
        __syncthreads();
    }
    if (i < N_NODES) offsets[i + 1] = s[t];
    if (t == 255) chunksums[b] = s[255];
}

__global__ void scan_sums(int* __restrict__ chunksums, int nchunks) {
    __shared__ int s[256];
    int t = threadIdx.x;
    int v = (t < nchunks) ? chunksums[t] : 0;
    s[t] = v;
    __syncthreads();
    for (int d = 1; d < 256; d <<= 1) {
        int add = (t >= d) ? s[t - d] : 0;
        __syncthreads();
        s[t] += add;
        __syncthreads();
    }
    if (t < nchunks) chunksums[t] = (t == 0) ? 0 : s[t - 1];
}

__global__ void finalize_offsets(int* __restrict__ offsets, const int* __restrict__ chunkoffs) {
    int i = blockIdx.x * blockDim.x + threadIdx.x;
    if (i < N_NODES) offsets[i + 1] += chunkoffs[i / 256];
    if (i == 0) offsets[0] = 0;
}

__global__ void init_cursor(const int* __restrict__ offsets, int* __restrict__ cursor) {
    int i = blockIdx.x * blockDim.x + threadIdx.x;
    if (i < N_NODES) cursor[i] = offsets[i];
}

__global__ void scatter_edges(const int* __restrict__ rowi, const int* __restrict__ coli,
                              int* __restrict__ cursor, int* __restrict__ csr_src) {
    int e = blockIdx.x * blockDim.x + threadIdx.x;
    if (e < N_EDGES) {
        int r = rowi[e], c = coli[e];
        int p = atomicAdd(&cursor[c], 1);
        csr_src[p] = r;
    }
}

// ---------------- weight transpose + bf16 cast: W [K][Nn] f32 -> Wt [Nn][K] bf16 ----------------

__global__ void transp_bf16(const float* __restrict__ W, short* __restrict__ Wt, int K, int Nn) {
    int idx = blockIdx.x * 256 + threadIdx.x;
    if (idx < K * Nn) {
        int n = idx / K, k = idx % K;
        Wt[idx] = f2bf(W[k * Nn + n]);
    }
}

// ---------------- layer 1: aggregate 3 feats (dis-factored), then tiny GEMM ----------------
// aggx[i] = dis_i * ( dis_i*x[i] + sum_r dis_r*x[r] )

__global__ void agg_feat3(const float* __restrict__ x, const int* __restrict__ offsets,
                          const int* __restrict__ csr_src, const float* __restrict__ dis,
                          float* __restrict__ aggx) {
    int i = blockIdx.x * blockDim.x + threadIdx.x;
    if (i >= N_NODES) return;
    float di = dis[i];
    float a0 = di * x[i * 3 + 0], a1 = di * x[i * 3 + 1], a2 = di * x[i * 3 + 2];
    int s = offsets[i], e = offsets[i + 1];
    int p = s;
    for (; p + 4 <= e; p += 4) {
        int r0 = csr_src[p], r1 = csr_src[p + 1], r2 = csr_src[p + 2], r3 = csr_src[p + 3];
        float d0 = dis[r0], d1 = dis[r1], d2 = dis[r2], d3 = dis[r3];
        float3 v0 = *(const float3*)&x[r0 * 3];
        float3 v1 = *(const float3*)&x[r1 * 3];
        float3 v2 = *(const float3*)&x[r2 * 3];
        float3 v3 = *(const float3*)&x[r3 * 3];
        a0 += d0 * v0.x + d1 * v1.x + d2 * v2.x + d3 * v3.x;
        a1 += d0 * v0.y + d1 * v1.y + d2 * v2.y + d3 * v3.y;
        a2 += d0 * v0.z + d1 * v1.z + d2 * v2.z + d3 * v3.z;
    }
    for (; p < e; ++p) {
        int r = csr_src[p];
        float dr = dis[r];
        a0 += dr * x[r * 3 + 0];
        a1 += dr * x[r * 3 + 1];
        a2 += dr * x[r * 3 + 2];
    }
    aggx[i * 3 + 0] = di * a0; aggx[i * 3 + 1] = di * a1; aggx[i * 3 + 2] = di * a2;
}

// h1' = dis_i * relu(aggx@W1 + b1)   (pre-scaled for next layer's aggregation)
__global__ void layer1(const float* __restrict__ aggx, const float* __restrict__ W1,
                       const float* __restrict__ b1, const float* __restrict__ dis,
                       short* __restrict__ h1) {
    int i = blockIdx.x;
    int t = threadIdx.x; // 256 threads, 2 channels each
    float di = dis[i];
    float a0 = aggx[i * 3 + 0], a1 = aggx[i * 3 + 1], a2 = aggx[i * 3 + 2];
    int j0 = 2 * t, j1 = 2 * t + 1;
    float v0 = di * fmaxf(a0 * W1[j0] + a1 * W1[C1 + j0] + a2 * W1[2 * C1 + j0] + b1[j0], 0.f);
    float v1 = di * fmaxf(a0 * W1[j1] + a1 * W1[C1 + j1] + a2 * W1[2 * C1 + j1] + b1[j1], 0.f);
    unsigned int pk = (unsigned int)(unsigned short)f2bf(v0) |
                      ((unsigned int)(unsigned short)f2bf(v1) << 16);
    ((unsigned int*)h1)[(size_t)i * (C1 / 2) + t] = pk;
}

// ---------------- bf16 MFMA GEMM: C[M x Nn] = A[M x K] * Bt^T, Bt is [Nn][K] bf16 ----------------

template <int K>
__global__ __launch_bounds__(256, 2) void gemm_bf16(const short* __restrict__ A,
                                                    const short* __restrict__ Bt,
                                                    short* __restrict__ Cmat, int M, int Nn) {
    __shared__ short As[128 * 32];
    __shared__ short Bs[64 * 32];
    int bm = blockIdx.x * 128, bn = blockIdx.y * 64;
    int t = threadIdx.x;
    int wave = t >> 6, lane = t & 63, quad = lane >> 4, l16 = lane & 15;
    int wm = (wave >> 1) * 64, wn = (wave & 1) * 32;
    f32x4 acc[4][2] = {};

    int ar = t >> 1, ak = (t & 1) * 16;       // A: 128 rows x 32 cols, 32B per thread
    int br = t >> 2, bk = (t & 3) * 8;        // B: 64 rows x 32 cols, 16B per thread
    int agr = bm + ar; if (agr > M - 1) agr = M - 1; // clamp: rows >= M never stored
    const short* aptr = A + (size_t)agr * K + ak;
    const short* bptr = Bt + (size_t)(bn + br) * K + bk;

    for (int k0 = 0; k0 < K; k0 += 32) {
        *(bh8*)&As[ar * 32 + ak]     = *(const bh8*)(aptr + k0);
        *(bh8*)&As[ar * 32 + ak + 8] = *(const bh8*)(aptr + k0 + 8);
        *(bh8*)&Bs[br * 32 + bk]     = *(const bh8*)(bptr + k0);
        __syncthreads();
        bh8 af[4], bf[2];
#pragma unroll
        for (int mt = 0; mt < 4; ++mt)
            af[mt] = *(const bh8*)&As[(wm + mt * 16 + l16) * 32 + quad * 8];
#pragma unroll
        for (int nt = 0; nt < 2; ++nt)
            bf[nt] = *(const bh8*)&Bs[(wn + nt * 16 + l16) * 32 + quad * 8];
#pragma unroll
        for (int mt = 0; mt < 4; ++mt)
#pragma unroll
            for (int nt = 0; nt < 2; ++nt)
                acc[mt][nt] = __builtin_amdgcn_mfma_f32_16x16x32_bf16(af[mt], bf[nt], acc[mt][nt], 0, 0, 0);
        __syncthreads();
    }

#pragma unroll
    for (int mt = 0; mt < 4; ++mt)
#pragma unroll
        for (int nt = 0; nt < 2; ++nt) {
            int colc = bn + wn + nt * 16 + l16;
#pragma unroll
            for (int r = 0; r < 4; ++r) {
                int rowc = bm + wm + mt * 16 + quad * 4 + r;
                if (rowc < M) Cmat[(size_t)rowc * Nn + colc] = f2bf(acc[mt][nt][r]);
            }
        }
}

// ---- unweighted aggregation (messages pre-scaled by dis[src]); block-per-node, x8 unroll ----
// out = [PRESCALE ? dis_i : 1] * relu( dis_i * (m[i] + sum_r m[r]) + bias )

template <int C, bool PRESCALE>
__global__ void aggregate_ns(const short* __restrict__ m, const int* __restrict__ offsets,
                             const int* __restrict__ csr_src, const float* __restrict__ dis,
                             const float* __restrict__ bias, short* __restrict__ out) {
    int i = blockIdx.x;
    int t = threadIdx.x; // C/2 threads, 2 channels each
    float di = dis[i];
    const unsigned int* mu = (const unsigned int*)m;
    unsigned int v = mu[(size_t)i * (C / 2) + t];
    float acc0 = bflo(v), acc1 = bfhi(v); // self term (already dis_i-scaled)
    int s = offsets[i], e = offsets[i + 1];
    int p = s;
    for (; p + 8 <= e; p += 8) {
        int r0 = csr_src[p],     r1 = csr_src[p + 1], r2 = csr_src[p + 2], r3 = csr_src[p + 3];
        int r4 = csr_src[p + 4], r5 = csr_src[p + 5], r6 = csr_src[p + 6], r7 = csr_src[p + 7];
        unsigned int u0 = mu[(size_t)r0 * (C / 2) + t];
        unsigned int u1 = mu[(size_t)r1 * (C / 2) + t];
        unsigned int u2 = mu[(size_t)r2 * (C / 2) + t];
        unsigned int u3 = mu[(size_t)r3 * (C / 2) + t];
        unsigned int u4 = mu[(size_t)r4 * (C / 2) + t];
        unsigned int u5 = mu[(size_t)r5 * (C / 2) + t];
        unsigned int u6 = mu[(size_t)r6 * (C / 2) + t];
        unsigned int u7 = mu[(size_t)r7 * (C / 2) + t];
        acc0 += bflo(u0) + bflo(u1) + bflo(u2) + bflo(u3) +
                bflo(u4) + bflo(u5) + bflo(u6) + bflo(u7);
        acc1 += bfhi(u0) + bfhi(u1) + bfhi(u2) + bfhi(u3) +
                bfhi(u4) + bfhi(u5) + bfhi(u6) + bfhi(u7);
    }
    for (; p < e; ++p) {
        int r = csr_src[p];
        unsigned int u = mu[(size_t)r * (C / 2) + t];
        acc0 += bflo(u);
        acc1 += bfhi(u);
    }
    acc0 = fmaxf(di * acc0 + bias[2 * t], 0.f);
    acc1 = fmaxf(di * acc1 + bias[2 * t + 1], 0.f);
    if (PRESCALE) { acc0 *= di; acc1 *= di; }
    unsigned int pk = (unsigned int)(unsigned short)f2bf(acc0) |
                      ((unsigned int)(unsigned short)f2bf(acc1) << 16);
    ((unsigned int*)out)[(size_t)i * (C / 2) + t] = pk;
}

// ---------------- two-stage mean pool: per-(graph,split) partial sums, few atomics ----------------

__global__ void pool_partial(const short* __restrict__ h3, const int* __restrict__ batch,
                             float* __restrict__ pooled) {
    int g = blockIdx.x, sp = blockIdx.y;
    int t = threadIdx.x; // 64 threads, 2 channels each (C3=128)
    __shared__ int seg[2];
    if (t < 2) {
        int target = g + t;
        int lo = 0, hi = N_NODES;
        while (lo < hi) { int mid = (lo + hi) >> 1; if (batch[mid] < target) lo = mid + 1; else hi = mid; }
        seg[t] = lo;
    }
    __syncthreads();
    int start = seg[0], end = seg[1];
    int len = end - start;
    int chunk = (len + PSPLIT - 1) / PSPLIT;
    int a = start + sp * chunk;
    int b = a + chunk; if (b > end) b = end;
    if (a >= b) return;
    const unsigned int* hu = (const unsigned int*)h3;
    float s0 = 0.f, s1 = 0.f;
    int i = a;
    for (; i + 4 <= b; i += 4) {
        unsigned int u0 = hu[(size_t)(i + 0) * (C3 / 2) + t];
        unsigned int u1 = hu[(size_t)(i + 1) * (C3 / 2) + t];
        unsigned int u2 = hu[(size_t)(i + 2) * (C3 / 2) + t];
        unsigned int u3 = hu[(size_t)(i + 3) * (C3 / 2) + t];
        s0 += bflo(u0) + bflo(u1) + bflo(u2) + bflo(u3);
        s1 += bfhi(u0) + bfhi(u1) + bfhi(u2) + bfhi(u3);
    }
    for (; i < b; ++i) {
        unsigned int u = hu[(size_t)i * (C3 / 2) + t];
        s0 += bflo(u);
        s1 += bfhi(u);
    }
    atomicAdd(&pooled[g * C3 + 2 * t], s0);
    atomicAdd(&pooled[g * C3 + 2 * t + 1], s1);
}

// ---------------- head: mean-divide + linear + log_softmax ----------------

__global__ void finalize_head(const float* __restrict__ pooled, const int* __restrict__ batch,
                              const float* __restrict__ Wc, const float* __restrict__ bc,
                              float* __restrict__ outp) {
    int g = blockIdx.x;
    int t = threadIdx.x; // 128 threads = C3
    __shared__ int seg[2];
    if (t < 2) {
        int target = g + t;
        int lo = 0, hi = N_NODES;
        while (lo < hi) { int mid = (lo + hi) >> 1; if (batch[mid] < target) lo = mid + 1; else hi = mid; }
        seg[t] = lo;
    }
    __syncthreads();
    float cnt = (float)(seg[1] - seg[0]);
    float pv = pooled[(size_t)g * C3 + t] / fmaxf(cnt, 1.f);
    float p0 = pv * Wc[t * 2 + 0];
    float p1 = pv * Wc[t * 2 + 1];
#pragma unroll
    for (int o = 32; o > 0; o >>= 1) {
        p0 += __shfl_down(p0, o);
        p1 += __shfl_down(p1, o);
    }
    __shared__ float r0[2], r1[2];
    int wid = t >> 6, lane = t & 63;
    if (lane == 0) { r0[wid] = p0; r1[wid] = p1; }
    __syncthreads();
    if (t == 0) {
        float l0 = r0[0] + r0[1] + bc[0];
        float l1 = r1[0] + r1[1] + bc[1];
        float mx = fmaxf(l0, l1);
        float lse = mx + logf(expf(l0 - mx) + expf(l1 - mx));
        outp[g * 2 + 0] = l0 - lse;
        outp[g * 2 + 1] = l1 - lse;
    }
}

// ---------------- launch ----------------

extern "C" void kernel_launch(void* const* d_in, const int* in_sizes, int n_in,
                              void* d_out, int out_size, void* d_ws, size_t ws_size,
                              hipStream_t stream) {
    const float* x = (const float*)d_in[0];
    const float* W1 = (const float*)d_in[1];
    const float* b1 = (const float*)d_in[2];
    const float* W2 = (const float*)d_in[3];
    const float* b2 = (const float*)d_in[4];
    const float* W3 = (const float*)d_in[5];
    const float* b3 = (const float*)d_in[6];
    const float* Wc = (const float*)d_in[7];
    const float* bc = (const float*)d_in[8];
    const int* ei = (const int*)d_in[9];
    const int* batch = (const int*)d_in[10];
    const int* row = ei;
    const int* col = ei + N_EDGES;
    float* out = (float*)d_out;

    char* ws = (char*)d_ws;
    size_t off = 0;
    auto alloc = [&](size_t bytes) -> void* {
        off = (off + 255) & ~(size_t)255;
        void* p = ws + off;
        off += bytes;
        return p;
    };

    int* counts = (int*)alloc((size_t)N_NODES * 4);
    int* offsets = (int*)alloc((size_t)(N_NODES + 1) * 4);
    int* cursor = (int*)alloc((size_t)N_NODES * 4);
    int* chunksums = (int*)alloc(256 * 4);
    float* dis = (float*)alloc((size_t)N_NODES * 4);
    int* csr_src = (int*)alloc((size_t)N_EDGES * 4);
    float* aggx = (float*)alloc((size_t)N_NODES * 3 * 4);
    short* W2t = (short*)alloc((size_t)C1 * C2 * 2);   // [C2][C1] bf16
    short* W3t = (short*)alloc((size_t)C2 * C3 * 2);   // [C3][C2] bf16
    short* h1 = (short*)alloc((size_t)N_NODES * C1 * 2);
    short* m2 = (short*)alloc((size_t)N_NODES * C2 * 2);
    short* h2 = (short*)alloc((size_t)N_NODES * C2 * 2);
    short* m3 = (short*)alloc((size_t)N_NODES * C3 * 2);
    short* h3 = (short*)alloc((size_t)N_NODES * C3 * 2);
    float* pooled = (float*)alloc((size_t)NGRAPH * C3 * 4);

    hipMemsetAsync(counts, 0, (size_t)N_NODES * 4, stream);
    hipMemsetAsync(pooled, 0, (size_t)NGRAPH * C3 * 4, stream);
    count_edges<<<(N_EDGES + 255) / 256, 256, 0, stream>>>(col, counts);
    compute_dis<<<(N_NODES + 255) / 256, 256, 0, stream>>>(counts, dis);
    int nchunks = (N_NODES + 255) / 256;
    scan_chunks<<<nchunks, 256, 0, stream>>>(counts, offsets, chunksums);
    scan_sums<<<1, 256, 0, stream>>>(chunksums, nchunks);
    finalize_offsets<<<(N_NODES + 255) / 256, 256, 0, stream>>>(offsets, chunksums);
    init_cursor<<<(N_NODES + 255) / 256, 256, 0, stream>>>(offsets, cursor);
    scatter_edges<<<(N_EDGES + 255) / 256, 256, 0, stream>>>(row, col, cursor, csr_src);

    transp_bf16<<<(C1 * C2 + 255) / 256, 256, 0, stream>>>(W2, W2t, C1, C2);
    transp_bf16<<<(C2 * C3 + 255) / 256, 256, 0, stream>>>(W3, W3t, C2, C3);

    agg_feat3<<<(N_NODES + 255) / 256, 256, 0, stream>>>(x, offsets, csr_src, dis, aggx);
    layer1<<<N_NODES, C1 / 2, 0, stream>>>(aggx, W1, b1, dis, h1);

    dim3 g2((N_NODES + 127) / 128, C2 / 64);
    gemm_bf16<C1><<<g2, 256, 0, stream>>>(h1, W2t, m2, N_NODES, C2);
    aggregate_ns<C2, true><<<N_NODES, C2 / 2, 0, stream>>>(m2, offsets, csr_src, dis, b2, h2);

    dim3 g3((N_NODES + 127) / 128, C3 / 64);
    gemm_bf16<C2><<<g3, 256, 0, stream>>>(h2, W3t, m3, N_NODES, C3);
    aggregate_ns<C3, false><<<N_NODES, C3 / 2, 0, stream>>>(m3, offsets, csr_src, dis, b3, h3);

    dim3 gp(NGRAPH, PSPLIT);
    pool_partial<<<gp, C3 / 2, 0, stream>>>(h3, batch, pooled);
    finalize_head<<<NGRAPH, C3, 0, stream>>>(pooled, batch, Wc, bc, out);
}

// Round 7
// 347.881 us; speedup vs baseline: 1.1616x; 1.0957x over previous
//
#include <hip/hip_runtime.h>
#include <hip/hip_bf16.h>
#include <math.h>

#define N_NODES 50000
#define N_EDGES 800000
#define NFEAT 3
#define C1 512
#define C2 256
#define C3 128
#define NGRAPH 100
#define NCLS 2
#define PSPLIT 8

typedef short bh8 __attribute__((ext_vector_type(8)));   // 8 bf16 bit-patterns (4 VGPRs)
typedef float f32x4 __attribute__((ext_vector_type(4))); // MFMA accumulator

__device__ __forceinline__ short f2bf(float x) {
    __hip_bfloat16 h = __float2bfloat16(x);
    return *reinterpret_cast<short*>(&h);
}
__device__ __forceinline__ float bflo(unsigned int u) { return __uint_as_float(u << 16); }
__device__ __forceinline__ float bfhi(unsigned int u) { return __uint_as_float(u & 0xffff0000u); }

// ---------------- degree count ----------------

__global__ void count_edges(const int* __restrict__ col, int* __restrict__ counts) {
    int e = blockIdx.x * blockDim.x + threadIdx.x;
    if (e < N_EDGES) atomicAdd(&counts[col[e]], 1);
}

// ---------------- CSR build: scan (fused dis) + scatter ----------------

__global__ void scan_chunks(const int* __restrict__ counts, int* __restrict__ offsets,
                            int* __restrict__ chunksums, float* __restrict__ dis) {
    __shared__ int s[256];
    int b = blockIdx.x, t = threadIdx.x;
    int i = b * 256 + t;
    int v = (i < N_NODES) ? counts[i] : 0;
    if (i < N_NODES) dis[i] = rsqrtf((float)(v + 1)); // +1 self loop
    s[t] = v;
    __syncthreads();
    for (int d = 1; d < 256; d <<= 1) {
        int add = (t >= d) ? s[t - d] : 0;
        __syncthreads();
        s[t] += add;
        __syncthreads();
    }
    if (i < N_NODES) offsets[i + 1] = s[t];
    if (t == 255) chunksums[b] = s[255];
}

__global__ void scan_sums(int* __restrict__ chunksums, int nchunks) {
    __shared__ int s[256];
    int t = threadIdx.x;
    int v = (t < nchunks) ? chunksums[t] : 0;
    s[t] = v;
    __syncthreads();
    for (int d = 1; d < 256; d <<= 1) {
        int add = (t >= d) ? s[t - d] : 0;
        __syncthreads();
        s[t] += add;
        __syncthreads();
    }
    if (t < nchunks) chunksums[t] = (t == 0) ? 0 : s[t - 1];
}

// also initializes cursor[] = final offsets (no separate init kernel)
__global__ void finalize_offsets(int* __restrict__ offsets, const int* __restrict__ chunkoffs,
                                 int* __restrict__ cursor) {
    int i = blockIdx.x * blockDim.x + threadIdx.x;
    if (i < N_NODES) {
        int v = offsets[i + 1] + chunkoffs[i / 256];
        offsets[i + 1] = v;
        if (i + 1 < N_NODES) cursor[i + 1] = v;
    }
    if (i == 0) { offsets[0] = 0; cursor[0] = 0; }
}

__global__ void scatter_edges(const int* __restrict__ rowi, const int* __restrict__ coli,
                              int* __restrict__ cursor, unsigned short* __restrict__ csr_src) {
    int e = blockIdx.x * blockDim.x + threadIdx.x;
    if (e < N_EDGES) {
        int r = rowi[e], c = coli[e];
        int p = atomicAdd(&cursor[c], 1);
        csr_src[p] = (unsigned short)r; // N_NODES < 65536
    }
}

// ---------------- weight transpose + bf16 cast (both layers in one kernel) ----------------

__global__ void prep_weights(const float* __restrict__ W2, const float* __restrict__ W3,
                             short* __restrict__ W2t, short* __restrict__ W3t) {
    int idx = blockIdx.x * 256 + threadIdx.x;
    if (idx < C1 * C2) {
        int n = idx / C1, k = idx % C1;
        W2t[idx] = f2bf(W2[k * C2 + n]);
    } else if (idx < C1 * C2 + C2 * C3) {
        int j = idx - C1 * C2;
        int n = j / C2, k = j % C2;
        W3t[j] = f2bf(W3[k * C3 + n]);
    }
}

// ---------------- layer 1: aggregate 3 feats (dis-factored) ----------------
// aggx[i] = dis_i * ( dis_i*x[i] + sum_r dis_r*x[r] )

__global__ void agg_feat3(const float* __restrict__ x, const int* __restrict__ offsets,
                          const unsigned short* __restrict__ csr_src, const float* __restrict__ dis,
                          float* __restrict__ aggx) {
    int i = blockIdx.x * blockDim.x + threadIdx.x;
    if (i >= N_NODES) return;
    float di = dis[i];
    float a0 = di * x[i * 3 + 0], a1 = di * x[i * 3 + 1], a2 = di * x[i * 3 + 2];
    int s = offsets[i], e = offsets[i + 1];
    int p = s;
    for (; p + 4 <= e; p += 4) {
        int r0 = csr_src[p], r1 = csr_src[p + 1], r2 = csr_src[p + 2], r3 = csr_src[p + 3];
        float d0 = dis[r0], d1 = dis[r1], d2 = dis[r2], d3 = dis[r3];
        float3 v0 = *(const float3*)&x[r0 * 3];
        float3 v1 = *(const float3*)&x[r1 * 3];
        float3 v2 = *(const float3*)&x[r2 * 3];
        float3 v3 = *(const float3*)&x[r3 * 3];
        a0 += d0 * v0.x + d1 * v1.x + d2 * v2.x + d3 * v3.x;
        a1 += d0 * v0.y + d1 * v1.y + d2 * v2.y + d3 * v3.y;
        a2 += d0 * v0.z + d1 * v1.z + d2 * v2.z + d3 * v3.z;
    }
    for (; p < e; ++p) {
        int r = csr_src[p];
        float dr = dis[r];
        a0 += dr * x[r * 3 + 0];
        a1 += dr * x[r * 3 + 1];
        a2 += dr * x[r * 3 + 2];
    }
    aggx[i * 3 + 0] = di * a0; aggx[i * 3 + 1] = di * a1; aggx[i * 3 + 2] = di * a2;
}

// ---- layer1 GEMM: 16 nodes per block, W1 staged in LDS; h1' = dis_i*relu(aggx@W1+b1) ----
#define L1_NB 16
__global__ __launch_bounds__(256) void layer1(const float* __restrict__ aggx,
                                              const float* __restrict__ W1,
                                              const float* __restrict__ b1,
                                              const float* __restrict__ dis,
                                              short* __restrict__ h1) {
    __shared__ float sW[3 * C1];
    __shared__ float sb[C1];
    __shared__ float sa[L1_NB * 3];
    __shared__ float sd[L1_NB];
    int t = threadIdx.x; // 256
    int base = blockIdx.x * L1_NB; // 3125 * 16 = 50000 exact
    for (int j = t; j < 3 * C1; j += 256) sW[j] = W1[j];
    for (int j = t; j < C1; j += 256) sb[j] = b1[j];
    if (t < L1_NB * 3) sa[t] = aggx[base * 3 + t];
    if (t < L1_NB) sd[t] = dis[base + t];
    __syncthreads();
    int j0 = 2 * t, j1 = 2 * t + 1;
    float w00 = sW[j0], w01 = sW[C1 + j0], w02 = sW[2 * C1 + j0];
    float w10 = sW[j1], w11 = sW[C1 + j1], w12 = sW[2 * C1 + j1];
    float bb0 = sb[j0], bb1 = sb[j1];
    unsigned int* h1u = (unsigned int*)h1;
#pragma unroll
    for (int n = 0; n < L1_NB; ++n) {
        int i = base + n;
        float a0 = sa[n * 3], a1 = sa[n * 3 + 1], a2 = sa[n * 3 + 2], di = sd[n];
        float v0 = di * fmaxf(a0 * w00 + a1 * w01 + a2 * w02 + bb0, 0.f);
        float v1 = di * fmaxf(a0 * w10 + a1 * w11 + a2 * w12 + bb1, 0.f);
        unsigned int pk = (unsigned int)(unsigned short)f2bf(v0) |
                          ((unsigned int)(unsigned short)f2bf(v1) << 16);
        h1u[(size_t)i * (C1 / 2) + t] = pk;
    }
}

// ------- bf16 MFMA GEMM, full-width N tile: C[M x BN] = A[M x K] * Bt^T, Bt=[BN][K] -------
// 512 threads = 8 waves in 2x4; wave tile 64 x (BN/4). A tile read exactly once (grid.y==1).

template <int K, int BN>
__global__ __launch_bounds__(512, 4) void gemm_bf16(const short* __restrict__ A,
                                                    const short* __restrict__ Bt,
                                                    short* __restrict__ Cmat, int M) {
    __shared__ short As[128 * 32];
    __shared__ short Bs[BN * 32];
    constexpr int NT = BN / 64; // 16-wide mfma tiles per wave
    int bm = blockIdx.x * 128;
    int t = threadIdx.x;
    int wave = t >> 6, lane = t & 63, quad = lane >> 4, l16 = lane & 15;
    int wm = (wave >> 2) * 64;
    int wn = (wave & 3) * (BN / 4);
    f32x4 acc[4][NT] = {};

    // A staging: 128x32 shorts, 8 per thread
    int ar = t >> 2, ak = (t & 3) * 8;
    int agr = bm + ar; if (agr > M - 1) agr = M - 1;
    const short* aptr = A + (size_t)agr * K + ak;

    for (int k0 = 0; k0 < K; k0 += 32) {
        *(bh8*)&As[ar * 32 + ak] = *(const bh8*)(aptr + k0);
        if constexpr (BN == 256) {
            int br = t >> 1, bk = (t & 1) * 16;
            const short* bptr = Bt + (size_t)br * K + bk + k0;
            *(bh8*)&Bs[br * 32 + bk]     = *(const bh8*)bptr;
            *(bh8*)&Bs[br * 32 + bk + 8] = *(const bh8*)(bptr + 8);
        } else { // BN == 128
            int br = t >> 2, bk = (t & 3) * 8;
            *(bh8*)&Bs[br * 32 + bk] = *(const bh8*)(Bt + (size_t)br * K + bk + k0);
        }
        __syncthreads();
        bh8 af[4], bf[NT];
#pragma unroll
        for (int mt = 0; mt < 4; ++mt)
            af[mt] = *(const bh8*)&As[(wm + mt * 16 + l16) * 32 + quad * 8];
#pragma unroll
        for (int nt = 0; nt < NT; ++nt)
            bf[nt] = *(const bh8*)&Bs[(wn + nt * 16 + l16) * 32 + quad * 8];
#pragma unroll
        for (int mt = 0; mt < 4; ++mt)
#pragma unroll
            for (int nt = 0; nt < NT; ++nt)
                acc[mt][nt] = __builtin_amdgcn_mfma_f32_16x16x32_bf16(af[mt], bf[nt], acc[mt][nt], 0, 0, 0);
        __syncthreads();
    }

#pragma unroll
    for (int mt = 0; mt < 4; ++mt)
#pragma unroll
        for (int nt = 0; nt < NT; ++nt) {
            int colc = wn + nt * 16 + l16;
#pragma unroll
            for (int r = 0; r < 4; ++r) {
                int rowc = bm + wm + mt * 16 + quad * 4 + r;
                if (rowc < M) Cmat[(size_t)rowc * BN + colc] = f2bf(acc[mt][nt][r]);
            }
        }
}

// ---- unweighted aggregation (messages pre-scaled by dis[src]); persistent grid-stride ----
// out = [PRESCALE ? dis_i : 1] * relu( dis_i * (m[i] + sum_r m[r]) + bias )

template <int C, bool PRESCALE>
__global__ __launch_bounds__(256) void aggregate_ns(const short* __restrict__ m,
        const int* __restrict__ offsets, const unsigned short* __restrict__ csr_src,
        const float* __restrict__ dis, const float* __restrict__ bias,
        short* __restrict__ out) {
    constexpr int TPN = C / 2;        // threads per node
    constexpr int NPB = 256 / TPN;    // nodes per block-iteration
    int sub = threadIdx.x / TPN;
    int t = threadIdx.x % TPN;
    const unsigned int* mu = (const unsigned int*)m;
    unsigned int* ou = (unsigned int*)out;
    float b0 = bias[2 * t], b1v = bias[2 * t + 1];
    for (int i = blockIdx.x * NPB + sub; i < N_NODES; i += gridDim.x * NPB) {
        float di = dis[i];
        unsigned int v = mu[(size_t)i * TPN + t];
        float acc0 = bflo(v), acc1 = bfhi(v); // self term (already dis_i-scaled)
        int s = offsets[i], e = offsets[i + 1];
        int p = s;
        for (; p + 8 <= e; p += 8) {
            int r0 = csr_src[p],     r1 = csr_src[p + 1], r2 = csr_src[p + 2], r3 = csr_src[p + 3];
            int r4 = csr_src[p + 4], r5 = csr_src[p + 5], r6 = csr_src[p + 6], r7 = csr_src[p + 7];
            unsigned int u0 = mu[(size_t)r0 * TPN + t];
            unsigned int u1 = mu[(size_t)r1 * TPN + t];
            unsigned int u2 = mu[(size_t)r2 * TPN + t];
            unsigned int u3 = mu[(size_t)r3 * TPN + t];
            unsigned int u4 = mu[(size_t)r4 * TPN + t];
            unsigned int u5 = mu[(size_t)r5 * TPN + t];
            unsigned int u6 = mu[(size_t)r6 * TPN + t];
            unsigned int u7 = mu[(size_t)r7 * TPN + t];
            acc0 += bflo(u0) + bflo(u1) + bflo(u2) + bflo(u3) +
                    bflo(u4) + bflo(u5) + bflo(u6) + bflo(u7);
            acc1 += bfhi(u0) + bfhi(u1) + bfhi(u2) + bfhi(u3) +
                    bfhi(u4) + bfhi(u5) + bfhi(u6) + bfhi(u7);
        }
        for (; p < e; ++p) {
            int r = csr_src[p];
            unsigned int u = mu[(size_t)r * TPN + t];
            acc0 += bflo(u);
            acc1 += bfhi(u);
        }
        acc0 = fmaxf(di * acc0 + b0, 0.f);
        acc1 = fmaxf(di * acc1 + b1v, 0.f);
        if (PRESCALE) { acc0 *= di; acc1 *= di; }
        unsigned int pk = (unsigned int)(unsigned short)f2bf(acc0) |
                          ((unsigned int)(unsigned short)f2bf(acc1) << 16);
        ou[(size_t)i * TPN + t] = pk;
    }
}

// ---------------- two-stage mean pool: per-(graph,split) partial sums, few atomics ----------------

__global__ void pool_partial(const short* __restrict__ h3, const int* __restrict__ batch,
                             float* __restrict__ pooled) {
    int g = blockIdx.x, sp = blockIdx.y;
    int t = threadIdx.x; // 64 threads, 2 channels each (C3=128)
    __shared__ int seg[2];
    if (t < 2) {
        int target = g + t;
        int lo = 0, hi = N_NODES;
        while (lo < hi) { int mid = (lo + hi) >> 1; if (batch[mid] < target) lo = mid + 1; else hi = mid; }
        seg[t] = lo;
    }
    __syncthreads();
    int start = seg[0], end = seg[1];
    int len = end - start;
    int chunk = (len + PSPLIT - 1) / PSPLIT;
    int a = start + sp * chunk;
    int b = a + chunk; if (b > end) b = end;
    if (a >= b) return;
    const unsigned int* hu = (const unsigned int*)h3;
    float s0 = 0.f, s1 = 0.f;
    int i = a;
    for (; i + 4 <= b; i += 4) {
        unsigned int u0 = hu[(size_t)(i + 0) * (C3 / 2) + t];
        unsigned int u1 = hu[(size_t)(i + 1) * (C3 / 2) + t];
        unsigned int u2 = hu[(size_t)(i + 2) * (C3 / 2) + t];
        unsigned int u3 = hu[(size_t)(i + 3) * (C3 / 2) + t];
        s0 += bflo(u0) + bflo(u1) + bflo(u2) + bflo(u3);
        s1 += bfhi(u0) + bfhi(u1) + bfhi(u2) + bfhi(u3);
    }
    for (; i < b; ++i) {
        unsigned int u = hu[(size_t)i * (C3 / 2) + t];
        s0 += bflo(u);
        s1 += bfhi(u);
    }
    atomicAdd(&pooled[g * C3 + 2 * t], s0);
    atomicAdd(&pooled[g * C3 + 2 * t + 1], s1);
}

// ---------------- head: mean-divide + linear + log_softmax ----------------

__global__ void finalize_head(const float* __restrict__ pooled, const int* __restrict__ batch,
                              const float* __restrict__ Wc, const float* __restrict__ bc,
                              float* __restrict__ outp) {
    int g = blockIdx.x;
    int t = threadIdx.x; // 128 threads = C3
    __shared__ int seg[2];
    if (t < 2) {
        int target = g + t;
        int lo = 0, hi = N_NODES;
        while (lo < hi) { int mid = (lo + hi) >> 1; if (batch[mid] < target) lo = mid + 1; else hi = mid; }
        seg[t] = lo;
    }
    __syncthreads();
    float cnt = (float)(seg[1] - seg[0]);
    float pv = pooled[(size_t)g * C3 + t] / fmaxf(cnt, 1.f);
    float p0 = pv * Wc[t * 2 + 0];
    float p1 = pv * Wc[t * 2 + 1];
#pragma unroll
    for (int o = 32; o > 0; o >>= 1) {
        p0 += __shfl_down(p0, o);
        p1 += __shfl_down(p1, o);
    }
    __shared__ float r0[2], r1[2];
    int wid = t >> 6, lane = t & 63;
    if (lane == 0) { r0[wid] = p0; r1[wid] = p1; }
    __syncthreads();
    if (t == 0) {
        float l0 = r0[0] + r0[1] + bc[0];
        float l1 = r1[0] + r1[1] + bc[1];
        float mx = fmaxf(l0, l1);
        float lse = mx + logf(expf(l0 - mx) + expf(l1 - mx));
        outp[g * 2 + 0] = l0 - lse;
        outp[g * 2 + 1] = l1 - lse;
    }
}

// ---------------- launch ----------------

extern "C" void kernel_launch(void* const* d_in, const int* in_sizes, int n_in,
                              void* d_out, int out_size, void* d_ws, size_t ws_size,
                              hipStream_t stream) {
    const float* x = (const float*)d_in[0];
    const float* W1 = (const float*)d_in[1];
    const float* b1 = (const float*)d_in[2];
    const float* W2 = (const float*)d_in[3];
    const float* b2 = (const float*)d_in[4];
    const float* W3 = (const float*)d_in[5];
    const float* b3 = (const float*)d_in[6];
    const float* Wc = (const float*)d_in[7];
    const float* bc = (const float*)d_in[8];
    const int* ei = (const int*)d_in[9];
    const int* batch = (const int*)d_in[10];
    const int* row = ei;
    const int* col = ei + N_EDGES;
    float* out = (float*)d_out;

    char* ws = (char*)d_ws;
    size_t off = 0;
    auto alloc = [&](size_t bytes) -> void* {
        off = (off + 255) & ~(size_t)255;
        void* p = ws + off;
        off += bytes;
        return p;
    };

    int* counts = (int*)alloc((size_t)N_NODES * 4);
    int* offsets = (int*)alloc((size_t)(N_NODES + 1) * 4);
    int* cursor = (int*)alloc((size_t)N_NODES * 4);
    int* chunksums = (int*)alloc(256 * 4);
    float* dis = (float*)alloc((size_t)N_NODES * 4);
    unsigned short* csr_src = (unsigned short*)alloc((size_t)N_EDGES * 2);
    float* aggx = (float*)alloc((size_t)N_NODES * 3 * 4);
    short* W2t = (short*)alloc((size_t)C1 * C2 * 2);   // [C2][C1] bf16
    short* W3t = (short*)alloc((size_t)C2 * C3 * 2);   // [C3][C2] bf16
    short* h1 = (short*)alloc((size_t)N_NODES * C1 * 2);
    short* m2 = (short*)alloc((size_t)N_NODES * C2 * 2);
    short* h2 = (short*)alloc((size_t)N_NODES * C2 * 2);
    short* m3 = (short*)alloc((size_t)N_NODES * C3 * 2);
    short* h3 = (short*)alloc((size_t)N_NODES * C3 * 2);
    float* pooled = (float*)alloc((size_t)NGRAPH * C3 * 4);

    hipMemsetAsync(counts, 0, (size_t)N_NODES * 4, stream);
    hipMemsetAsync(pooled, 0, (size_t)NGRAPH * C3 * 4, stream);
    count_edges<<<(N_EDGES + 255) / 256, 256, 0, stream>>>(col, counts);
    int nchunks = (N_NODES + 255) / 256;
    scan_chunks<<<nchunks, 256, 0, stream>>>(counts, offsets, chunksums, dis);
    scan_sums<<<1, 256, 0, stream>>>(chunksums, nchunks);
    finalize_offsets<<<(N_NODES + 255) / 256, 256, 0, stream>>>(offsets, chunksums, cursor);
    scatter_edges<<<(N_EDGES + 255) / 256, 256, 0, stream>>>(row, col, cursor, csr_src);

    prep_weights<<<(C1 * C2 + C2 * C3 + 255) / 256, 256, 0, stream>>>(W2, W3, W2t, W3t);

    agg_feat3<<<(N_NODES + 255) / 256, 256, 0, stream>>>(x, offsets, csr_src, dis, aggx);
    layer1<<<N_NODES / L1_NB, 256, 0, stream>>>(aggx, W1, b1, dis, h1);

    gemm_bf16<C1, C2><<<(N_NODES + 127) / 128, 512, 0, stream>>>(h1, W2t, m2, N_NODES);
    aggregate_ns<C2, true><<<2048, 256, 0, stream>>>(m2, offsets, csr_src, dis, b2, h2);

    gemm_bf16<C2, C3><<<(N_NODES + 127) / 128, 512, 0, stream>>>(h2, W3t, m3, N_NODES);
    aggregate_ns<C3, false><<<2048, 256, 0, stream>>>(m3, offsets, csr_src, dis, b3, h3);

    dim3 gp(NGRAPH, PSPLIT);
    pool_partial<<<gp, C3 / 2, 0, stream>>>(h3, batch, pooled);
    finalize_head<<<NGRAPH, C3, 0, stream>>>(pooled, batch, Wc, bc, out);
}

// Round 8
// 336.760 us; speedup vs baseline: 1.2000x; 1.0330x over previous
//
#include <hip/hip_runtime.h>
#include <hip/hip_bf16.h>
#include <math.h>

#define N_NODES 50000
#define N_EDGES 800000
#define NFEAT 3
#define C1 512
#define C2 256
#define C3 128
#define NGRAPH 100
#define NCLS 2
#define PSPLIT 8

typedef short bh8 __attribute__((ext_vector_type(8)));   // 8 bf16 bit-patterns (4 VGPRs)
typedef float f32x4 __attribute__((ext_vector_type(4))); // MFMA accumulator

__device__ __forceinline__ short f2bf(float x) {
    __hip_bfloat16 h = __float2bfloat16(x);
    return *reinterpret_cast<short*>(&h);
}
__device__ __forceinline__ float bflo(unsigned int u) { return __uint_as_float(u << 16); }
__device__ __forceinline__ float bfhi(unsigned int u) { return __uint_as_float(u & 0xffff0000u); }

// ---------------- degree count ----------------

__global__ void count_edges(const int* __restrict__ col, int* __restrict__ counts) {
    int e = blockIdx.x * blockDim.x + threadIdx.x;
    if (e < N_EDGES) atomicAdd(&counts[col[e]], 1);
}

// ---------------- CSR build: scan (fused dis) + scatter ----------------

__global__ void scan_chunks(const int* __restrict__ counts, int* __restrict__ offsets,
                            int* __restrict__ chunksums, float* __restrict__ dis) {
    __shared__ int s[256];
    int b = blockIdx.x, t = threadIdx.x;
    int i = b * 256 + t;
    int v = (i < N_NODES) ? counts[i] : 0;
    if (i < N_NODES) dis[i] = rsqrtf((float)(v + 1)); // +1 self loop
    s[t] = v;
    __syncthreads();
    for (int d = 1; d < 256; d <<= 1) {
        int add = (t >= d) ? s[t - d] : 0;
        __syncthreads();
        s[t] += add;
        __syncthreads();
    }
    if (i < N_NODES) offsets[i + 1] = s[t];
    if (t == 255) chunksums[b] = s[255];
}

__global__ void scan_sums(int* __restrict__ chunksums, int nchunks) {
    __shared__ int s[256];
    int t = threadIdx.x;
    int v = (t < nchunks) ? chunksums[t] : 0;
    s[t] = v;
    __syncthreads();
    for (int d = 1; d < 256; d <<= 1) {
        int add = (t >= d) ? s[t - d] : 0;
        __syncthreads();
        s[t] += add;
        __syncthreads();
    }
    if (t < nchunks) chunksums[t] = (t == 0) ? 0 : s[t - 1];
}

// also initializes cursor[] = final offsets (no separate init kernel)
__global__ void finalize_offsets(int* __restrict__ offsets, const int* __restrict__ chunkoffs,
                                 int* __restrict__ cursor) {
    int i = blockIdx.x * blockDim.x + threadIdx.x;
    if (i < N_NODES) {
        int v = offsets[i + 1] + chunkoffs[i / 256];
        offsets[i + 1] = v;
        if (i + 1 < N_NODES) cursor[i + 1] = v;
    }
    if (i == 0) { offsets[0] = 0; cursor[0] = 0; }
}

__global__ void scatter_edges(const int* __restrict__ rowi, const int* __restrict__ coli,
                              int* __restrict__ cursor, int* __restrict__ csr_src) {
    int e = blockIdx.x * blockDim.x + threadIdx.x;
    if (e < N_EDGES) {
        int r = rowi[e], c = coli[e];
        int p = atomicAdd(&cursor[c], 1);
        csr_src[p] = r;
    }
}

// ---------------- weight transpose + bf16 cast (both layers in one kernel) ----------------

__global__ void prep_weights(const float* __restrict__ W2, const float* __restrict__ W3,
                             short* __restrict__ W2t, short* __restrict__ W3t) {
    int idx = blockIdx.x * 256 + threadIdx.x;
    if (idx < C1 * C2) {
        int n = idx / C1, k = idx % C1;
        W2t[idx] = f2bf(W2[k * C2 + n]);
    } else if (idx < C1 * C2 + C2 * C3) {
        int j = idx - C1 * C2;
        int n = j / C2, k = j % C2;
        W3t[j] = f2bf(W3[k * C3 + n]);
    }
}

// ---------------- layer 1: aggregate 3 feats (dis-factored) ----------------
// aggx[i] = dis_i * ( dis_i*x[i] + sum_r dis_r*x[r] )

__global__ void agg_feat3(const float* __restrict__ x, const int* __restrict__ offsets,
                          const int* __restrict__ csr_src, const float* __restrict__ dis,
                          float* __restrict__ aggx) {
    int i = blockIdx.x * blockDim.x + threadIdx.x;
    if (i >= N_NODES) return;
    float di = dis[i];
    float a0 = di * x[i * 3 + 0], a1 = di * x[i * 3 + 1], a2 = di * x[i * 3 + 2];
    int s = offsets[i], e = offsets[i + 1];
    int p = s;
    for (; p + 4 <= e; p += 4) {
        int r0 = csr_src[p], r1 = csr_src[p + 1], r2 = csr_src[p + 2], r3 = csr_src[p + 3];
        float d0 = dis[r0], d1 = dis[r1], d2 = dis[r2], d3 = dis[r3];
        float3 v0 = *(const float3*)&x[r0 * 3];
        float3 v1 = *(const float3*)&x[r1 * 3];
        float3 v2 = *(const float3*)&x[r2 * 3];
        float3 v3 = *(const float3*)&x[r3 * 3];
        a0 += d0 * v0.x + d1 * v1.x + d2 * v2.x + d3 * v3.x;
        a1 += d0 * v0.y + d1 * v1.y + d2 * v2.y + d3 * v3.y;
        a2 += d0 * v0.z + d1 * v1.z + d2 * v2.z + d3 * v3.z;
    }
    for (; p < e; ++p) {
        int r = csr_src[p];
        float dr = dis[r];
        a0 += dr * x[r * 3 + 0];
        a1 += dr * x[r * 3 + 1];
        a2 += dr * x[r * 3 + 2];
    }
    aggx[i * 3 + 0] = di * a0; aggx[i * 3 + 1] = di * a1; aggx[i * 3 + 2] = di * a2;
}

// ---- layer1 GEMM: 16 nodes per block, W1 staged in LDS; h1' = dis_i*relu(aggx@W1+b1) ----
#define L1_NB 16
__global__ __launch_bounds__(256) void layer1(const float* __restrict__ aggx,
                                              const float* __restrict__ W1,
                                              const float* __restrict__ b1,
                                              const float* __restrict__ dis,
                                              short* __restrict__ h1) {
    __shared__ float sW[3 * C1];
    __shared__ float sb[C1];
    __shared__ float sa[L1_NB * 3];
    __shared__ float sd[L1_NB];
    int t = threadIdx.x; // 256
    int base = blockIdx.x * L1_NB; // 3125 * 16 = 50000 exact
    for (int j = t; j < 3 * C1; j += 256) sW[j] = W1[j];
    for (int j = t; j < C1; j += 256) sb[j] = b1[j];
    if (t < L1_NB * 3) sa[t] = aggx[base * 3 + t];
    if (t < L1_NB) sd[t] = dis[base + t];
    __syncthreads();
    int j0 = 2 * t, j1 = 2 * t + 1;
    float w00 = sW[j0], w01 = sW[C1 + j0], w02 = sW[2 * C1 + j0];
    float w10 = sW[j1], w11 = sW[C1 + j1], w12 = sW[2 * C1 + j1];
    float bb0 = sb[j0], bb1 = sb[j1];
    unsigned int* h1u = (unsigned int*)h1;
#pragma unroll
    for (int n = 0; n < L1_NB; ++n) {
        int i = base + n;
        float a0 = sa[n * 3], a1 = sa[n * 3 + 1], a2 = sa[n * 3 + 2], di = sd[n];
        float v0 = di * fmaxf(a0 * w00 + a1 * w01 + a2 * w02 + bb0, 0.f);
        float v1 = di * fmaxf(a0 * w10 + a1 * w11 + a2 * w12 + bb1, 0.f);
        unsigned int pk = (unsigned int)(unsigned short)f2bf(v0) |
                          ((unsigned int)(unsigned short)f2bf(v1) << 16);
        h1u[(size_t)i * (C1 / 2) + t] = pk;
    }
}

// ------- bf16 MFMA GEMM, full-width N tile: C[M x BN] = A[M x K] * Bt^T, Bt=[BN][K] -------
// 512 threads = 8 waves in 2x4; wave tile 64 x (BN/4). A tile read exactly once (grid.y==1).

template <int K, int BN>
__global__ __launch_bounds__(512, 4) void gemm_bf16(const short* __restrict__ A,
                                                    const short* __restrict__ Bt,
                                                    short* __restrict__ Cmat, int M) {
    __shared__ short As[128 * 32];
    __shared__ short Bs[BN * 32];
    constexpr int NT = BN / 64; // 16-wide mfma tiles per wave
    int bm = blockIdx.x * 128;
    int t = threadIdx.x;
    int wave = t >> 6, lane = t & 63, quad = lane >> 4, l16 = lane & 15;
    int wm = (wave >> 2) * 64;
    int wn = (wave & 3) * (BN / 4);
    f32x4 acc[4][NT] = {};

    // A staging: 128x32 shorts, 8 per thread
    int ar = t >> 2, ak = (t & 3) * 8;
    int agr = bm + ar; if (agr > M - 1) agr = M - 1;
    const short* aptr = A + (size_t)agr * K + ak;

    for (int k0 = 0; k0 < K; k0 += 32) {
        *(bh8*)&As[ar * 32 + ak] = *(const bh8*)(aptr + k0);
        if constexpr (BN == 256) {
            int br = t >> 1, bk = (t & 1) * 16;
            const short* bptr = Bt + (size_t)br * K + bk + k0;
            *(bh8*)&Bs[br * 32 + bk]     = *(const bh8*)bptr;
            *(bh8*)&Bs[br * 32 + bk + 8] = *(const bh8*)(bptr + 8);
        } else { // BN == 128
            int br = t >> 2, bk = (t & 3) * 8;
            *(bh8*)&Bs[br * 32 + bk] = *(const bh8*)(Bt + (size_t)br * K + bk + k0);
        }
        __syncthreads();
        bh8 af[4], bf[NT];
#pragma unroll
        for (int mt = 0; mt < 4; ++mt)
            af[mt] = *(const bh8*)&As[(wm + mt * 16 + l16) * 32 + quad * 8];
#pragma unroll
        for (int nt = 0; nt < NT; ++nt)
            bf[nt] = *(const bh8*)&Bs[(wn + nt * 16 + l16) * 32 + quad * 8];
#pragma unroll
        for (int mt = 0; mt < 4; ++mt)
#pragma unroll
            for (int nt = 0; nt < NT; ++nt)
                acc[mt][nt] = __builtin_amdgcn_mfma_f32_16x16x32_bf16(af[mt], bf[nt], acc[mt][nt], 0, 0, 0);
        __syncthreads();
    }

#pragma unroll
    for (int mt = 0; mt < 4; ++mt)
#pragma unroll
        for (int nt = 0; nt < NT; ++nt) {
            int colc = wn + nt * 16 + l16;
#pragma unroll
            for (int r = 0; r < 4; ++r) {
                int rowc = bm + wm + mt * 16 + quad * 4 + r;
                if (rowc < M) Cmat[(size_t)rowc * BN + colc] = f2bf(acc[mt][nt][r]);
            }
        }
}

// ---- unweighted aggregation (messages pre-scaled by dis[src]); block-per-node, x8 unroll ----
// out = [PRESCALE ? dis_i : 1] * relu( dis_i * (m[i] + sum_r m[r]) + bias )

template <int C, bool PRESCALE>
__global__ void aggregate_ns(const short* __restrict__ m, const int* __restrict__ offsets,
                             const int* __restrict__ csr_src, const float* __restrict__ dis,
                             const float* __restrict__ bias, short* __restrict__ out) {
    int i = blockIdx.x;
    int t = threadIdx.x; // C/2 threads, 2 channels each
    float di = dis[i];
    const unsigned int* mu = (const unsigned int*)m;
    unsigned int v = mu[(size_t)i * (C / 2) + t];
    float acc0 = bflo(v), acc1 = bfhi(v); // self term (already dis_i-scaled)
    int s = offsets[i], e = offsets[i + 1];
    int p = s;
    for (; p + 8 <= e; p += 8) {
        int r0 = csr_src[p],     r1 = csr_src[p + 1], r2 = csr_src[p + 2], r3 = csr_src[p + 3];
        int r4 = csr_src[p + 4], r5 = csr_src[p + 5], r6 = csr_src[p + 6], r7 = csr_src[p + 7];
        unsigned int u0 = mu[(size_t)r0 * (C / 2) + t];
        unsigned int u1 = mu[(size_t)r1 * (C / 2) + t];
        unsigned int u2 = mu[(size_t)r2 * (C / 2) + t];
        unsigned int u3 = mu[(size_t)r3 * (C / 2) + t];
        unsigned int u4 = mu[(size_t)r4 * (C / 2) + t];
        unsigned int u5 = mu[(size_t)r5 * (C / 2) + t];
        unsigned int u6 = mu[(size_t)r6 * (C / 2) + t];
        unsigned int u7 = mu[(size_t)r7 * (C / 2) + t];
        acc0 += bflo(u0) + bflo(u1) + bflo(u2) + bflo(u3) +
                bflo(u4) + bflo(u5) + bflo(u6) + bflo(u7);
        acc1 += bfhi(u0) + bfhi(u1) + bfhi(u2) + bfhi(u3) +
                bfhi(u4) + bfhi(u5) + bfhi(u6) + bfhi(u7);
    }
    for (; p < e; ++p) {
        int r = csr_src[p];
        unsigned int u = mu[(size_t)r * (C / 2) + t];
        acc0 += bflo(u);
        acc1 += bfhi(u);
    }
    acc0 = fmaxf(di * acc0 + bias[2 * t], 0.f);
    acc1 = fmaxf(di * acc1 + bias[2 * t + 1], 0.f);
    if (PRESCALE) { acc0 *= di; acc1 *= di; }
    unsigned int pk = (unsigned int)(unsigned short)f2bf(acc0) |
                      ((unsigned int)(unsigned short)f2bf(acc1) << 16);
    ((unsigned int*)out)[(size_t)i * (C / 2) + t] = pk;
}

// ---------------- two-stage mean pool: per-(graph,split) partial sums, few atomics ----------------

__global__ void pool_partial(const short* __restrict__ h3, const int* __restrict__ batch,
                             float* __restrict__ pooled) {
    int g = blockIdx.x, sp = blockIdx.y;
    int t = threadIdx.x; // 64 threads, 2 channels each (C3=128)
    __shared__ int seg[2];
    if (t < 2) {
        int target = g + t;
        int lo = 0, hi = N_NODES;
        while (lo < hi) { int mid = (lo + hi) >> 1; if (batch[mid] < target) lo = mid + 1; else hi = mid; }
        seg[t] = lo;
    }
    __syncthreads();
    int start = seg[0], end = seg[1];
    int len = end - start;
    int chunk = (len + PSPLIT - 1) / PSPLIT;
    int a = start + sp * chunk;
    int b = a + chunk; if (b > end) b = end;
    if (a >= b) return;
    const unsigned int* hu = (const unsigned int*)h3;
    float s0 = 0.f, s1 = 0.f;
    int i = a;
    for (; i + 4 <= b; i += 4) {
        unsigned int u0 = hu[(size_t)(i + 0) * (C3 / 2) + t];
        unsigned int u1 = hu[(size_t)(i + 1) * (C3 / 2) + t];
        unsigned int u2 = hu[(size_t)(i + 2) * (C3 / 2) + t];
        unsigned int u3 = hu[(size_t)(i + 3) * (C3 / 2) + t];
        s0 += bflo(u0) + bflo(u1) + bflo(u2) + bflo(u3);
        s1 += bfhi(u0) + bfhi(u1) + bfhi(u2) + bfhi(u3);
    }
    for (; i < b; ++i) {
        unsigned int u = hu[(size_t)i * (C3 / 2) + t];
        s0 += bflo(u);
        s1 += bfhi(u);
    }
    atomicAdd(&pooled[g * C3 + 2 * t], s0);
    atomicAdd(&pooled[g * C3 + 2 * t + 1], s1);
}

// ---------------- head: mean-divide + linear + log_softmax ----------------

__global__ void finalize_head(const float* __restrict__ pooled, const int* __restrict__ batch,
                              const float* __restrict__ Wc, const float* __restrict__ bc,
                              float* __restrict__ outp) {
    int g = blockIdx.x;
    int t = threadIdx.x; // 128 threads = C3
    __shared__ int seg[2];
    if (t < 2) {
        int target = g + t;
        int lo = 0, hi = N_NODES;
        while (lo < hi) { int mid = (lo + hi) >> 1; if (batch[mid] < target) lo = mid + 1; else hi = mid; }
        seg[t] = lo;
    }
    __syncthreads();
    float cnt = (float)(seg[1] - seg[0]);
    float pv = pooled[(size_t)g * C3 + t] / fmaxf(cnt, 1.f);
    float p0 = pv * Wc[t * 2 + 0];
    float p1 = pv * Wc[t * 2 + 1];
#pragma unroll
    for (int o = 32; o > 0; o >>= 1) {
        p0 += __shfl_down(p0, o);
        p1 += __shfl_down(p1, o);
    }
    __shared__ float r0[2], r1[2];
    int wid = t >> 6, lane = t & 63;
    if (lane == 0) { r0[wid] = p0; r1[wid] = p1; }
    __syncthreads();
    if (t == 0) {
        float l0 = r0[0] + r0[1] + bc[0];
        float l1 = r1[0] + r1[1] + bc[1];
        float mx = fmaxf(l0, l1);
        float lse = mx + logf(expf(l0 - mx) + expf(l1 - mx));
        outp[g * 2 + 0] = l0 - lse;
        outp[g * 2 + 1] = l1 - lse;
    }
}

// ---------------- launch ----------------

extern "C" void kernel_launch(void* const* d_in, const int* in_sizes, int n_in,
                              void* d_out, int out_size, void* d_ws, size_t ws_size,
                              hipStream_t stream) {
    const float* x = (const float*)d_in[0];
    const float* W1 = (const float*)d_in[1];
    const float* b1 = (const float*)d_in[2];
    const float* W2 = (const float*)d_in[3];
    const float* b2 = (const float*)d_in[4];
    const float* W3 = (const float*)d_in[5];
    const float* b3 = (const float*)d_in[6];
    const float* Wc = (const float*)d_in[7];
    const float* bc = (const float*)d_in[8];
    const int* ei = (const int*)d_in[9];
    const int* batch = (const int*)d_in[10];
    const int* row = ei;
    const int* col = ei + N_EDGES;
    float* out = (float*)d_out;

    char* ws = (char*)d_ws;
    size_t off = 0;
    auto alloc = [&](size_t bytes) -> void* {
        off = (off + 255) & ~(size_t)255;
        void* p = ws + off;
        off += bytes;
        return p;
    };

    int* counts = (int*)alloc((size_t)N_NODES * 4);
    int* offsets = (int*)alloc((size_t)(N_NODES + 1) * 4);
    int* cursor = (int*)alloc((size_t)N_NODES * 4);
    int* chunksums = (int*)alloc(256 * 4);
    float* dis = (float*)alloc((size_t)N_NODES * 4);
    int* csr_src = (int*)alloc((size_t)N_EDGES * 4);
    float* aggx = (float*)alloc((size_t)N_NODES * 3 * 4);
    short* W2t = (short*)alloc((size_t)C1 * C2 * 2);   // [C2][C1] bf16
    short* W3t = (short*)alloc((size_t)C2 * C3 * 2);   // [C3][C2] bf16
    short* h1 = (short*)alloc((size_t)N_NODES * C1 * 2);
    short* m2 = (short*)alloc((size_t)N_NODES * C2 * 2);
    short* h2 = (short*)alloc((size_t)N_NODES * C2 * 2);
    short* m3 = (short*)alloc((size_t)N_NODES * C3 * 2);
    short* h3 = (short*)alloc((size_t)N_NODES * C3 * 2);
    float* pooled = (float*)alloc((size_t)NGRAPH * C3 * 4);

    hipMemsetAsync(counts, 0, (size_t)N_NODES * 4, stream);
    hipMemsetAsync(pooled, 0, (size_t)NGRAPH * C3 * 4, stream);
    count_edges<<<(N_EDGES + 255) / 256, 256, 0, stream>>>(col, counts);
    int nchunks = (N_NODES + 255) / 256;
    scan_chunks<<<nchunks, 256, 0, stream>>>(counts, offsets, chunksums, dis);
    scan_sums<<<1, 256, 0, stream>>>(chunksums, nchunks);
    finalize_offsets<<<(N_NODES + 255) / 256, 256, 0, stream>>>(offsets, chunksums, cursor);
    scatter_edges<<<(N_EDGES + 255) / 256, 256, 0, stream>>>(row, col, cursor, csr_src);

    prep_weights<<<(C1 * C2 + C2 * C3 + 255) / 256, 256, 0, stream>>>(W2, W3, W2t, W3t);

    agg_feat3<<<(N_NODES + 255) / 256, 256, 0, stream>>>(x, offsets, csr_src, dis, aggx);
    layer1<<<N_NODES / L1_NB, 256, 0, stream>>>(aggx, W1, b1, dis, h1);

    gemm_bf16<C1, C2><<<(N_NODES + 127) / 128, 512, 0, stream>>>(h1, W2t, m2, N_NODES);
    aggregate_ns<C2, true><<<N_NODES, C2 / 2, 0, stream>>>(m2, offsets, csr_src, dis, b2, h2);

    gemm_bf16<C2, C3><<<(N_NODES + 127) / 128, 512, 0, stream>>>(h2, W3t, m3, N_NODES);
    aggregate_ns<C3, false><<<N_NODES, C3 / 2, 0, stream>>>(m3, offsets, csr_src, dis, b3, h3);

    dim3 gp(NGRAPH, PSPLIT);
    pool_partial<<<gp, C3 / 2, 0, stream>>>(h3, batch, pooled);
    finalize_head<<<NGRAPH, C3, 0, stream>>>(pooled, batch, Wc, bc, out);
}